// Round 1
// baseline (710.771 us; speedup 1.0000x reference)
//
#include <hip/hip_runtime.h>
#include <cmath>

typedef __bf16 bf16x8 __attribute__((ext_vector_type(8)));
typedef float f32x4 __attribute__((ext_vector_type(4)));
typedef unsigned short u16;

#define MODE_PLAIN 0
#define MODE_GELU  1
#define MODE_TANH  2

__device__ __forceinline__ u16 f2bf(float f) {
  union { float f; unsigned int u; } v; v.f = f;
  unsigned int u = v.u;
  return (u16)((u + 0x7FFFu + ((u >> 16) & 1u)) >> 16);
}

__device__ __forceinline__ float geluf(float x) {
  return 0.5f * x * (1.0f + erff(x * 0.7071067811865475f));
}

// ---------------- elementwise f32 -> bf16 (8 elems/thread) ----------------
__global__ __launch_bounds__(256) void cvt_bf16(const float* __restrict__ in,
                                                u16* __restrict__ out, int n8) {
  int i = blockIdx.x * 256 + threadIdx.x;
  if (i >= n8) return;
  const float4* p = (const float4*)in + 2 * (size_t)i;
  float4 a = p[0], b = p[1];
  uint4 o;
  o.x = (unsigned)f2bf(a.x) | ((unsigned)f2bf(a.y) << 16);
  o.y = (unsigned)f2bf(a.z) | ((unsigned)f2bf(a.w) << 16);
  o.z = (unsigned)f2bf(b.x) | ((unsigned)f2bf(b.y) << 16);
  o.w = (unsigned)f2bf(b.z) | ((unsigned)f2bf(b.w) << 16);
  ((uint4*)out)[i] = o;
}

// ---------- LDS-tiled transpose + cvt: in (R x C) f32 -> out (C x R) bf16 ----------
__global__ __launch_bounds__(256) void transpose_cvt(const float* __restrict__ in,
                                                     u16* __restrict__ out,
                                                     int R, int C) {
  __shared__ float tile[64][65];
  const int t = threadIdx.x;
  const int c0 = blockIdx.x * 64, r0 = blockIdx.y * 64;
  const int lr = t >> 6, lc = t & 63;
#pragma unroll
  for (int p = 0; p < 16; ++p) {
    int r = p * 4 + lr;
    float v = 0.f;
    if (r0 + r < R && c0 + lc < C) v = in[(size_t)(r0 + r) * C + c0 + lc];
    tile[r][lc] = v;
  }
  __syncthreads();
#pragma unroll
  for (int p = 0; p < 16; ++p) {
    int c = p * 4 + lr;
    if (c0 + c < C && r0 + lc < R)
      out[(size_t)(c0 + c) * R + r0 + lc] = f2bf(tile[lc][c]);
  }
}

// ---------------- generic bf16 MFMA GEMM: C = A(MxK) * Bt(NxK)^T ----------------
// WRxWC waves, each wave computes 64x64 (4x4 frags of 16x16), BK=64.
template <int WR, int WC, int MODE>
__global__ __launch_bounds__(256) void gemm_bt(const u16* __restrict__ A,
                                               const u16* __restrict__ Bt,
                                               float* __restrict__ C,
                                               u16* __restrict__ auxBf,
                                               float* __restrict__ auxF,
                                               int M, int N, int K) {
  constexpr int BM = WR * 64, BN = WC * 64;
  __shared__ __attribute__((aligned(16))) u16 As[BM][72];
  __shared__ __attribute__((aligned(16))) u16 Bs[BN][72];
  const int tid = threadIdx.x;
  const int wid = tid >> 6, lane = tid & 63;
  const int l16 = lane & 15, quad = lane >> 4;
  const int wm = (wid % WR) * 64, wn = (wid / WR) * 64;
  const int m0 = blockIdx.y * BM, n0 = blockIdx.x * BN;

  f32x4 acc[4][4] = {};

  const int kIters = K >> 6;
  for (int kt = 0; kt < kIters; ++kt) {
    __syncthreads();
    for (int c = tid; c < BM * 8; c += 256) {
      int r = c >> 3, ko = (c & 7) << 3;
      *(uint4*)(&As[r][ko]) =
          *(const uint4*)(A + (size_t)(m0 + r) * K + kt * 64 + ko);
    }
    for (int c = tid; c < BN * 8; c += 256) {
      int r = c >> 3, ko = (c & 7) << 3;
      *(uint4*)(&Bs[r][ko]) =
          *(const uint4*)(Bt + (size_t)(n0 + r) * K + kt * 64 + ko);
    }
    __syncthreads();
    bf16x8 af[4][2], bfr[4][2];
#pragma unroll
    for (int mt = 0; mt < 4; ++mt)
#pragma unroll
      for (int ks = 0; ks < 2; ++ks)
        af[mt][ks] = *(const bf16x8*)(&As[wm + mt * 16 + l16][ks * 32 + quad * 8]);
#pragma unroll
    for (int nt = 0; nt < 4; ++nt)
#pragma unroll
      for (int ks = 0; ks < 2; ++ks)
        bfr[nt][ks] = *(const bf16x8*)(&Bs[wn + nt * 16 + l16][ks * 32 + quad * 8]);
#pragma unroll
    for (int mt = 0; mt < 4; ++mt)
#pragma unroll
      for (int nt = 0; nt < 4; ++nt)
#pragma unroll
        for (int ks = 0; ks < 2; ++ks)
          acc[mt][nt] = __builtin_amdgcn_mfma_f32_16x16x32_bf16(
              af[mt][ks], bfr[nt][ks], acc[mt][nt], 0, 0, 0);
  }

#pragma unroll
  for (int mt = 0; mt < 4; ++mt)
#pragma unroll
    for (int nt = 0; nt < 4; ++nt)
#pragma unroll
      for (int r = 0; r < 4; ++r) {
        int row = m0 + wm + mt * 16 + quad * 4 + r;
        int col = n0 + wn + nt * 16 + l16;
        float v = acc[mt][nt][r];
        if constexpr (MODE == MODE_PLAIN) {
          C[(size_t)row * N + col] = v;
        } else if constexpr (MODE == MODE_GELU) {
          C[(size_t)row * N + col] = v;
          auxBf[(size_t)row * N + col] = f2bf(geluf(v));
        } else {  // MODE_TANH: N==64, C=tok_q [s][32], auxF=tok_v [s][32]
          float tv = tanhf(v);
          if (col < 32) C[(size_t)row * 32 + col] = tv;
          else          auxF[(size_t)row * 32 + (col - 32)] = tv;
        }
      }
}

// ---------------- prep: tau scaling + RoPE + layouts for attention ----------------
// qkv fp32 (2048x3072) -> Qb[h][s][d] bf16, Kb[kv][s][d] bf16, Vt[kv][d][s] bf16
__global__ __launch_bounds__(256) void prep_qkv(const float* __restrict__ qkv,
                                                const float* __restrict__ tokq,
                                                const float* __restrict__ tokv,
                                                const float* __restrict__ alpha,
                                                const float* __restrict__ cosb,
                                                const float* __restrict__ sinb,
                                                const int* __restrict__ pos_ids,
                                                u16* __restrict__ Qb,
                                                u16* __restrict__ Kb,
                                                u16* __restrict__ Vt) {
  const int s = blockIdx.x;
  const int tid = threadIdx.x;
  __shared__ float cs[16], sn[16], tq_s[32], tv_s[32];
  if (tid < 16) { cs[tid] = cosb[s * 16 + tid]; sn[tid] = sinb[s * 16 + tid]; }
  if (tid < 32) {
    float p = (float)pos_ids[s] + 1.0f;
    float sig = 1.0f / (1.0f + __expf(-alpha[tid] * logf(p)));
    float taupos = 0.5f + sig;
    tq_s[tid] = tokq[s * 32 + tid] + taupos;
    tv_s[tid] = tokv[s * 32 + tid] + taupos;
  }
  __syncthreads();
  const float* row = qkv + (size_t)s * 3072;

  // Q: 32 heads x 64 dims (scale by tau_q, then rope)
  for (int idx = tid; idx < 2048; idx += 256) {
    int h = idx >> 6, d = idx & 63;
    float tq = tq_s[h];
    float v;
    if (d < 32) {
      int i = d >> 1;
      float xr = row[h * 64 + i] * tq, xi = row[h * 64 + 16 + i] * tq;
      v = (d & 1) ? (xr * sn[i] + xi * cs[i]) : (xr * cs[i] - xi * sn[i]);
    } else v = row[h * 64 + d] * tq;
    Qb[((size_t)h * 2048 + s) * 64 + d] = f2bf(v);
  }
  // K: 8 kv heads (rope only)
  for (int idx = tid; idx < 512; idx += 256) {
    int h = idx >> 6, d = idx & 63;
    const float* kr = row + 2048;
    float v;
    if (d < 32) {
      int i = d >> 1;
      float xr = kr[h * 64 + i], xi = kr[h * 64 + 16 + i];
      v = (d & 1) ? (xr * sn[i] + xi * cs[i]) : (xr * cs[i] - xi * sn[i]);
    } else v = kr[h * 64 + d];
    Kb[((size_t)h * 2048 + s) * 64 + d] = f2bf(v);
  }
  // V: 8 kv heads, scale by tau_v (first 8 of 32), store transposed [d][s]
  for (int idx = tid; idx < 512; idx += 256) {
    int h = idx >> 6, d = idx & 63;
    float v = row[2560 + h * 64 + d] * tv_s[h];
    Vt[((size_t)h * 64 + d) * 2048 + s] = f2bf(v);
  }
}

// ---------------- flash attention (causal, GQA 4:1) ----------------
// grid (S/64, H). block 256 = 4 waves x 16 q-rows. Ob[s][h*64+d] bf16.
__global__ __launch_bounds__(256) void flash_attn(const u16* __restrict__ Qb,
                                                  const u16* __restrict__ Kb,
                                                  const u16* __restrict__ Vt,
                                                  u16* __restrict__ Ob) {
  __shared__ __attribute__((aligned(16))) u16 Ks[64][72];
  __shared__ __attribute__((aligned(16))) u16 Vs[64][72];
  __shared__ __attribute__((aligned(16))) u16 Ps[64][72];
  const int qt = blockIdx.x, h = blockIdx.y, kvh = h >> 2;
  const int tid = threadIdx.x, wid = tid >> 6, lane = tid & 63;
  const int l16 = lane & 15, quad = lane >> 4;
  const int qrow = qt * 64 + wid * 16 + l16;

  bf16x8 qfrag[2];
  qfrag[0] = *(const bf16x8*)(Qb + ((size_t)(h * 2048 + qrow)) * 64 + quad * 8);
  qfrag[1] = *(const bf16x8*)(Qb + ((size_t)(h * 2048 + qrow)) * 64 + 32 + quad * 8);

  f32x4 oacc[4] = {};
  float mrun[4] = {-1e30f, -1e30f, -1e30f, -1e30f};
  float lrun[4] = {0.f, 0.f, 0.f, 0.f};

  const int kvTiles = qt + 1;
  for (int kt = 0; kt < kvTiles; ++kt) {
    __syncthreads();  // prev-iter Ks/Vs reads done
    {
      int c = tid;
#pragma unroll
      for (int cc = 0; cc < 2; ++cc, c += 256) {
        int r = c >> 3, ko = (c & 7) << 3;
        *(uint4*)(&Ks[r][ko]) =
            *(const uint4*)(Kb + ((size_t)(kvh * 2048 + kt * 64 + r)) * 64 + ko);
      }
      c = tid;
#pragma unroll
      for (int cc = 0; cc < 2; ++cc, c += 256) {
        int r = c >> 3, ko = (c & 7) << 3;  // r is d index
        *(uint4*)(&Vs[r][ko]) =
            *(const uint4*)(Vt + ((size_t)(kvh * 64 + r)) * 2048 + kt * 64 + ko);
      }
    }
    __syncthreads();

    // S = Q K^T
    f32x4 sacc[4] = {};
#pragma unroll
    for (int nt = 0; nt < 4; ++nt) {
      bf16x8 b0 = *(const bf16x8*)(&Ks[nt * 16 + l16][quad * 8]);
      bf16x8 b1 = *(const bf16x8*)(&Ks[nt * 16 + l16][32 + quad * 8]);
      sacc[nt] = __builtin_amdgcn_mfma_f32_16x16x32_bf16(qfrag[0], b0, sacc[nt], 0, 0, 0);
      sacc[nt] = __builtin_amdgcn_mfma_f32_16x16x32_bf16(qfrag[1], b1, sacc[nt], 0, 0, 0);
    }

    // online softmax (rows quad*4+r are wave-private; state replicated over 16 lanes)
    float al[4];
#pragma unroll
    for (int r = 0; r < 4; ++r) {
      const int qg = qt * 64 + wid * 16 + quad * 4 + r;
      float sv[4];
      float mx = -3e38f;
#pragma unroll
      for (int nt = 0; nt < 4; ++nt) {
        float s = sacc[nt][r] * 0.125f;
        int kg = kt * 64 + nt * 16 + l16;
        if (kg > qg) s = -1e30f;
        sv[nt] = s;
        mx = fmaxf(mx, s);
      }
      mx = fmaxf(mx, __shfl_xor(mx, 1));
      mx = fmaxf(mx, __shfl_xor(mx, 2));
      mx = fmaxf(mx, __shfl_xor(mx, 4));
      mx = fmaxf(mx, __shfl_xor(mx, 8));
      float mn = fmaxf(mrun[r], mx);
      float a = __expf(mrun[r] - mn);
      float ps = 0.f;
#pragma unroll
      for (int nt = 0; nt < 4; ++nt) {
        float p = __expf(sv[nt] - mn);
        ps += p;
        Ps[wid * 16 + quad * 4 + r][nt * 16 + l16] = f2bf(p);
      }
      ps += __shfl_xor(ps, 1);
      ps += __shfl_xor(ps, 2);
      ps += __shfl_xor(ps, 4);
      ps += __shfl_xor(ps, 8);
      lrun[r] = lrun[r] * a + ps;
      mrun[r] = mn;
      al[r] = a;
    }
#pragma unroll
    for (int nt = 0; nt < 4; ++nt)
#pragma unroll
      for (int r = 0; r < 4; ++r) oacc[nt][r] *= al[r];

    // O += P V  (P rows are wave-private: same-wave LDS write->read, no barrier)
#pragma unroll
    for (int ks = 0; ks < 2; ++ks) {
      bf16x8 pa = *(const bf16x8*)(&Ps[wid * 16 + l16][ks * 32 + quad * 8]);
#pragma unroll
      for (int nt = 0; nt < 4; ++nt) {
        bf16x8 vb = *(const bf16x8*)(&Vs[nt * 16 + l16][ks * 32 + quad * 8]);
        oacc[nt] = __builtin_amdgcn_mfma_f32_16x16x32_bf16(pa, vb, oacc[nt], 0, 0, 0);
      }
    }
  }

#pragma unroll
  for (int nt = 0; nt < 4; ++nt)
#pragma unroll
    for (int r = 0; r < 4; ++r) {
      float o = oacc[nt][r] / lrun[r];
      int srow = qt * 64 + wid * 16 + quad * 4 + r;
      int col = h * 64 + nt * 16 + l16;
      Ob[(size_t)srow * 2048 + col] = f2bf(o);
    }
}

// ---------------- launcher ----------------
extern "C" void kernel_launch(void* const* d_in, const int* in_sizes, int n_in,
                              void* d_out, int out_size, void* d_ws, size_t ws_size,
                              hipStream_t stream) {
  (void)in_sizes; (void)n_in; (void)out_size; (void)ws_size;
  const float* hidden = (const float*)d_in[0];
  const float* cosb   = (const float*)d_in[1];
  const float* sinb   = (const float*)d_in[2];
  const int*   pos    = (const int*)d_in[3];
  const float* Wq     = (const float*)d_in[4];
  const float* Wk     = (const float*)d_in[5];
  const float* Wv     = (const float*)d_in[6];
  const float* Wo     = (const float*)d_in[7];
  const float* tWq    = (const float*)d_in[8];
  const float* tWv    = (const float*)d_in[9];
  const float* alpha  = (const float*)d_in[10];
  float* out = (float*)d_out;

  char* ws = (char*)d_ws;
  size_t off = 0;
  auto alloc = [&](size_t bytes) -> void* {
    void* p = ws + off;
    off += (bytes + 255) & ~(size_t)255;
    return p;
  };
  u16*   Xb    = (u16*)alloc(2048ull * 2048 * 2);
  u16*   WqkvT = (u16*)alloc(3072ull * 2048 * 2);
  u16*   WoT   = (u16*)alloc(2048ull * 2048 * 2);
  u16*   Tt    = (u16*)alloc(64ull * 3072 * 2);
  float* qkv   = (float*)alloc(2048ull * 3072 * 4);
  u16*   featb = (u16*)alloc(2048ull * 3072 * 2);
  float* tokq  = (float*)alloc(2048ull * 32 * 4);
  float* tokv  = (float*)alloc(2048ull * 32 * 4);
  u16*   Qb    = (u16*)alloc(32ull * 2048 * 64 * 2);
  u16*   Kb    = (u16*)alloc(8ull * 2048 * 64 * 2);
  u16*   Vt    = (u16*)alloc(8ull * 64 * 2048 * 2);
  u16*   Ob    = (u16*)alloc(2048ull * 2048 * 2);

  // 1) dtype conversions / transposes
  cvt_bf16<<<2048, 256, 0, stream>>>(hidden, Xb, 2048 * 2048 / 8);
  transpose_cvt<<<dim3(32, 32), 256, 0, stream>>>(Wq, WqkvT, 2048, 2048);
  transpose_cvt<<<dim3(8, 32), 256, 0, stream>>>(Wk, WqkvT + 2048ull * 2048, 2048, 512);
  transpose_cvt<<<dim3(8, 32), 256, 0, stream>>>(Wv, WqkvT + 2560ull * 2048, 2048, 512);
  transpose_cvt<<<dim3(32, 32), 256, 0, stream>>>(Wo, WoT, 2048, 2048);
  transpose_cvt<<<dim3(1, 48), 256, 0, stream>>>(tWq, Tt, 3072, 32);
  transpose_cvt<<<dim3(1, 48), 256, 0, stream>>>(tWv, Tt + 32ull * 3072, 3072, 32);

  // 2) QKV projection (+fused gelu -> featb)
  gemm_bt<2, 2, MODE_GELU><<<dim3(24, 16), 256, 0, stream>>>(
      Xb, WqkvT, qkv, featb, nullptr, 2048, 3072, 2048);

  // 3) tok head-scaling GEMM (+tanh split epilogue)
  gemm_bt<4, 1, MODE_TANH><<<dim3(1, 8), 256, 0, stream>>>(
      featb, Tt, tokq, nullptr, tokv, 2048, 64, 3072);

  // 4) tau + rope + layout prep
  prep_qkv<<<2048, 256, 0, stream>>>(qkv, tokq, tokv, alpha, cosb, sinb, pos,
                                     Qb, Kb, Vt);

  // 5) causal flash attention
  flash_attn<<<dim3(32, 32), 256, 0, stream>>>(Qb, Kb, Vt, Ob);

  // 6) output projection
  gemm_bt<2, 2, MODE_PLAIN><<<dim3(16, 16), 256, 0, stream>>>(
      Ob, WoT, out, nullptr, nullptr, 2048, 2048, 2048);
}

// Round 2
// 379.730 us; speedup vs baseline: 1.8718x; 1.8718x over previous
//
#include <hip/hip_runtime.h>
#include <cmath>

typedef __bf16 bf16x8 __attribute__((ext_vector_type(8)));
typedef float f32x4 __attribute__((ext_vector_type(4)));
typedef unsigned short u16;
typedef unsigned int u32;

__device__ __forceinline__ u16 f2bf(float f) {
  union { float f; unsigned int u; } v; v.f = f;
  unsigned int u = v.u;
  return (u16)((u + 0x7FFFu + ((u >> 16) & 1u)) >> 16);
}

__device__ __forceinline__ float geluf(float x) {
  return 0.5f * x * (1.0f + erff(x * 0.7071067811865475f));
}

// async global->LDS, 16B per lane. LDS dest = wave-uniform base + lane*16.
__device__ __forceinline__ void gl_lds16(const void* g, void* l) {
  __builtin_amdgcn_global_load_lds(
      (const __attribute__((address_space(1))) u32*)g,
      (__attribute__((address_space(3))) u32*)l, 16, 0, 0);
}

// ---------------- elementwise f32 -> bf16 (8 elems/thread) ----------------
__global__ __launch_bounds__(256) void cvt_bf16(const float* __restrict__ in,
                                                u16* __restrict__ out, int n8) {
  int i = blockIdx.x * 256 + threadIdx.x;
  if (i >= n8) return;
  const float4* p = (const float4*)in + 2 * (size_t)i;
  float4 a = p[0], b = p[1];
  uint4 o;
  o.x = (unsigned)f2bf(a.x) | ((unsigned)f2bf(a.y) << 16);
  o.y = (unsigned)f2bf(a.z) | ((unsigned)f2bf(a.w) << 16);
  o.z = (unsigned)f2bf(b.x) | ((unsigned)f2bf(b.y) << 16);
  o.w = (unsigned)f2bf(b.z) | ((unsigned)f2bf(b.w) << 16);
  ((uint4*)out)[i] = o;
}

// ---------- LDS-tiled transpose + cvt: in (R x C) f32 -> out (C x R) bf16 ----------
__global__ __launch_bounds__(256) void transpose_cvt(const float* __restrict__ in,
                                                     u16* __restrict__ out,
                                                     int R, int C) {
  __shared__ float tile[64][65];
  const int t = threadIdx.x;
  const int c0 = blockIdx.x * 64, r0 = blockIdx.y * 64;
  const int lr = t >> 6, lc = t & 63;
#pragma unroll
  for (int p = 0; p < 16; ++p) {
    int r = p * 4 + lr;
    float v = 0.f;
    if (r0 + r < R && c0 + lc < C) v = in[(size_t)(r0 + r) * C + c0 + lc];
    tile[r][lc] = v;
  }
  __syncthreads();
#pragma unroll
  for (int p = 0; p < 16; ++p) {
    int c = p * 4 + lr;
    if (c0 + c < C && r0 + lc < R)
      out[(size_t)(c0 + c) * R + r0 + lc] = f2bf(tile[lc][c]);
  }
}

// ---------------- bf16 MFMA GEMM: Cpart[z] = A(MxK) * Bt(NxK)^T over K-chunk z --------
// 256 threads = WR*WC waves, each wave 64x64 (4x4 frags of 16x16x32), BK=64.
// LDS unpadded 64 u16/row with XOR chunk swizzle; staged via global_load_lds w=16.
template <int WR, int WC>
__global__ __launch_bounds__(256, 3) void gemm_bt(const u16* __restrict__ A,
                                                  const u16* __restrict__ Bt,
                                                  float* __restrict__ Cpart,
                                                  int M, int N, int K, int kPer) {
  constexpr int BM = WR * 64, BN = WC * 64;
  __shared__ __attribute__((aligned(16))) u16 As[BM * 64];
  __shared__ __attribute__((aligned(16))) u16 Bs[BN * 64];
  const int tid = threadIdx.x, wid = tid >> 6, lane = tid & 63;
  const int l16 = lane & 15, quad = lane >> 4;
  const int wm = (wid % WR) * 64, wn = (wid / WR) * 64;
  const int m0 = blockIdx.y * BM, n0 = blockIdx.x * BN;
  const int kIters = K >> 6;
  const int kStart = blockIdx.z * kPer;
  const int kEnd = (kStart + kPer < kIters) ? (kStart + kPer) : kIters;

  const int lrow = lane >> 3;            // row within 8-row chunk
  const int swz = (lane & 7) ^ lrow;     // swizzled global 16B-chunk index
  const u16* gAb = A + (size_t)m0 * K + (size_t)swz * 8;
  const u16* gBb = Bt + (size_t)n0 * K + (size_t)swz * 8;
  const int sx = l16 & 7;

  f32x4 acc[4][4] = {};
  for (int kt = kStart; kt < kEnd; ++kt) {
    __syncthreads();
    const u16* gA = gAb + (size_t)kt * 64;
    const u16* gB = gBb + (size_t)kt * 64;
#pragma unroll
    for (int j = 0; j < BM / 32; ++j) {
      int i = wid * (BM / 32) + j;
      gl_lds16(gA + (size_t)(i * 8 + lrow) * K, &As[i * 512]);
    }
#pragma unroll
    for (int j = 0; j < BN / 32; ++j) {
      int i = wid * (BN / 32) + j;
      gl_lds16(gB + (size_t)(i * 8 + lrow) * K, &Bs[i * 512]);
    }
    __syncthreads();
    bf16x8 af[4][2], bfr[4][2];
#pragma unroll
    for (int mt = 0; mt < 4; ++mt)
#pragma unroll
      for (int ks = 0; ks < 2; ++ks)
        af[mt][ks] = *(const bf16x8*)(&As[(wm + mt * 16 + l16) * 64 +
                                          (((ks * 4 + quad) ^ sx) * 8)]);
#pragma unroll
    for (int nt = 0; nt < 4; ++nt)
#pragma unroll
      for (int ks = 0; ks < 2; ++ks)
        bfr[nt][ks] = *(const bf16x8*)(&Bs[(wn + nt * 16 + l16) * 64 +
                                           (((ks * 4 + quad) ^ sx) * 8)]);
#pragma unroll
    for (int mt = 0; mt < 4; ++mt)
#pragma unroll
      for (int nt = 0; nt < 4; ++nt)
#pragma unroll
        for (int ks = 0; ks < 2; ++ks)
          acc[mt][nt] = __builtin_amdgcn_mfma_f32_16x16x32_bf16(
              af[mt][ks], bfr[nt][ks], acc[mt][nt], 0, 0, 0);
  }

  float* C = Cpart + (size_t)blockIdx.z * M * N;
#pragma unroll
  for (int mt = 0; mt < 4; ++mt)
#pragma unroll
    for (int nt = 0; nt < 4; ++nt)
#pragma unroll
      for (int r = 0; r < 4; ++r) {
        int row = m0 + wm + mt * 16 + quad * 4 + r;
        int col = n0 + wn + nt * 16 + l16;
        C[(size_t)row * N + col] = acc[mt][nt][r];
      }
}

// ---------------- reduce kernels (split-K epilogues) ----------------
__global__ __launch_bounds__(256) void reduce_gelu(float* __restrict__ base, int P,
                                                   int n4, u16* __restrict__ gout) {
  int i = blockIdx.x * 256 + threadIdx.x;
  if (i >= n4) return;
  size_t n = (size_t)n4 * 4;
  float4 v = ((const float4*)base)[i];
  for (int p = 1; p < P; ++p) {
    float4 w = ((const float4*)(base + (size_t)p * n))[i];
    v.x += w.x; v.y += w.y; v.z += w.z; v.w += w.w;
  }
  if (P > 1) ((float4*)base)[i] = v;
  uint2 o;
  o.x = (u32)f2bf(geluf(v.x)) | ((u32)f2bf(geluf(v.y)) << 16);
  o.y = (u32)f2bf(geluf(v.z)) | ((u32)f2bf(geluf(v.w)) << 16);
  ((uint2*)gout)[i] = o;
}

__global__ __launch_bounds__(256) void reduce_add(const float* __restrict__ base, int P,
                                                  int n4, float* __restrict__ dst) {
  int i = blockIdx.x * 256 + threadIdx.x;
  if (i >= n4) return;
  size_t n = (size_t)n4 * 4;
  float4 v = ((const float4*)base)[i];
  for (int p = 1; p < P; ++p) {
    float4 w = ((const float4*)(base + (size_t)p * n))[i];
    v.x += w.x; v.y += w.y; v.z += w.z; v.w += w.w;
  }
  ((float4*)dst)[i] = v;
}

__global__ __launch_bounds__(256) void reduce_tanh(const float* __restrict__ base, int P,
                                                   int n, float* __restrict__ tokq,
                                                   float* __restrict__ tokv) {
  int i = blockIdx.x * 256 + threadIdx.x;
  if (i >= n) return;
  float v = base[i];
  for (int p = 1; p < P; ++p) v += base[(size_t)p * n + i];
  float t = tanhf(v);
  int col = i & 63, row = i >> 6;
  if (col < 32) tokq[row * 32 + col] = t;
  else          tokv[row * 32 + (col - 32)] = t;
}

// ---------------- prep: tau scaling + RoPE + layouts for attention ----------------
__global__ __launch_bounds__(256) void prep_qkv(const float* __restrict__ qkv,
                                                const float* __restrict__ tokq,
                                                const float* __restrict__ tokv,
                                                const float* __restrict__ alpha,
                                                const float* __restrict__ cosb,
                                                const float* __restrict__ sinb,
                                                const int* __restrict__ pos_ids,
                                                u16* __restrict__ Qb,
                                                u16* __restrict__ Kb,
                                                u16* __restrict__ Vt,
                                                u16* __restrict__ Vb) {
  const int s = blockIdx.x;
  const int tid = threadIdx.x;
  __shared__ float cs[16], sn[16], tq_s[32], tv_s[32];
  if (tid < 16) { cs[tid] = cosb[s * 16 + tid]; sn[tid] = sinb[s * 16 + tid]; }
  if (tid < 32) {
    float p = (float)pos_ids[s] + 1.0f;
    float sig = 1.0f / (1.0f + __expf(-alpha[tid] * logf(p)));
    float taupos = 0.5f + sig;
    tq_s[tid] = tokq[s * 32 + tid] + taupos;
    tv_s[tid] = tokv[s * 32 + tid] + taupos;
  }
  __syncthreads();
  const float* row = qkv + (size_t)s * 3072;

  for (int idx = tid; idx < 2048; idx += 256) {
    int h = idx >> 6, d = idx & 63;
    float tq = tq_s[h];
    float v;
    if (d < 32) {
      int i = d >> 1;
      float xr = row[h * 64 + i] * tq, xi = row[h * 64 + 16 + i] * tq;
      v = (d & 1) ? (xr * sn[i] + xi * cs[i]) : (xr * cs[i] - xi * sn[i]);
    } else v = row[h * 64 + d] * tq;
    Qb[((size_t)h * 2048 + s) * 64 + d] = f2bf(v);
  }
  for (int idx = tid; idx < 512; idx += 256) {
    int h = idx >> 6, d = idx & 63;
    const float* kr = row + 2048;
    float v;
    if (d < 32) {
      int i = d >> 1;
      float xr = kr[h * 64 + i], xi = kr[h * 64 + 16 + i];
      v = (d & 1) ? (xr * sn[i] + xi * cs[i]) : (xr * cs[i] - xi * sn[i]);
    } else v = kr[h * 64 + d];
    Kb[((size_t)h * 2048 + s) * 64 + d] = f2bf(v);
  }
  for (int idx = tid; idx < 512; idx += 256) {
    int h = idx >> 6, d = idx & 63;
    float v = row[2560 + h * 64 + d] * tv_s[h];
    u16 b = f2bf(v);
    if (Vb) Vb[((size_t)h * 2048 + s) * 64 + d] = b;       // coalesced, transposed later
    else    Vt[((size_t)h * 64 + d) * 2048 + s] = b;       // fallback: scattered
  }
}

// ---------------- bf16 transpose Vb[h][s][d] -> Vt[h][d][s] ----------------
__global__ __launch_bounds__(256) void vtrans(const u16* __restrict__ Vb,
                                              u16* __restrict__ Vt) {
  __shared__ u16 t[64][68];
  const int s0 = blockIdx.x * 64, h = blockIdx.y;
  const int tid = threadIdx.x;
  const u16* src = Vb + ((size_t)h * 2048 + s0) * 64;
#pragma unroll
  for (int p = 0; p < 4; ++p) {
    int v = p * 256 + tid;
    int r = v >> 4, c = (v & 15) * 4;
    uint2 w = *(const uint2*)(src + (size_t)r * 64 + c);
    t[r][c] = (u16)(w.x & 0xffff); t[r][c + 1] = (u16)(w.x >> 16);
    t[r][c + 2] = (u16)(w.y & 0xffff); t[r][c + 3] = (u16)(w.y >> 16);
  }
  __syncthreads();
  u16* dst = Vt + (size_t)h * 64 * 2048 + s0;
#pragma unroll
  for (int p = 0; p < 4; ++p) {
    int v = p * 256 + tid;
    int d = v >> 4, s = (v & 15) * 4;
    uint2 w;
    w.x = (u32)t[s][d] | ((u32)t[s + 1][d] << 16);
    w.y = (u32)t[s + 2][d] | ((u32)t[s + 3][d] << 16);
    *(uint2*)(dst + (size_t)d * 2048 + s) = w;
  }
}

// ---------------- flash attention (causal, GQA 4:1) ----------------
__global__ __launch_bounds__(256) void flash_attn(const u16* __restrict__ Qb,
                                                  const u16* __restrict__ Kb,
                                                  const u16* __restrict__ Vt,
                                                  u16* __restrict__ Ob) {
  __shared__ __attribute__((aligned(16))) u16 Ks[64 * 64];
  __shared__ __attribute__((aligned(16))) u16 Vs[64 * 64];
  __shared__ __attribute__((aligned(16))) u16 Ps[64][72];
  const int qt = blockIdx.x, h = blockIdx.y, kvh = h >> 2;
  const int tid = threadIdx.x, wid = tid >> 6, lane = tid & 63;
  const int l16 = lane & 15, quad = lane >> 4;
  const int lrow = lane >> 3;
  const int swz = (lane & 7) ^ lrow;
  const int sx = l16 & 7;
  const int qrow = qt * 64 + wid * 16 + l16;

  bf16x8 qfrag[2];
  qfrag[0] = *(const bf16x8*)(Qb + ((size_t)(h * 2048 + qrow)) * 64 + quad * 8);
  qfrag[1] = *(const bf16x8*)(Qb + ((size_t)(h * 2048 + qrow)) * 64 + 32 + quad * 8);

  f32x4 oacc[4] = {};
  float mrun[4] = {-1e30f, -1e30f, -1e30f, -1e30f};
  float lrun[4] = {0.f, 0.f, 0.f, 0.f};

  const int kvTiles = qt + 1;
  for (int kt = 0; kt < kvTiles; ++kt) {
    __syncthreads();
#pragma unroll
    for (int j = 0; j < 2; ++j) {
      int i = wid * 2 + j;
      gl_lds16(Kb + ((size_t)kvh * 2048 + (size_t)kt * 64 + i * 8 + lrow) * 64 + swz * 8,
               &Ks[i * 512]);
      gl_lds16(Vt + ((size_t)kvh * 64 + i * 8 + lrow) * 2048 + (size_t)kt * 64 + swz * 8,
               &Vs[i * 512]);
    }
    __syncthreads();

    f32x4 sacc[4] = {};
#pragma unroll
    for (int nt = 0; nt < 4; ++nt) {
      bf16x8 b0 = *(const bf16x8*)(&Ks[(nt * 16 + l16) * 64 + ((quad ^ sx) * 8)]);
      bf16x8 b1 = *(const bf16x8*)(&Ks[(nt * 16 + l16) * 64 + (((4 + quad) ^ sx) * 8)]);
      sacc[nt] = __builtin_amdgcn_mfma_f32_16x16x32_bf16(qfrag[0], b0, sacc[nt], 0, 0, 0);
      sacc[nt] = __builtin_amdgcn_mfma_f32_16x16x32_bf16(qfrag[1], b1, sacc[nt], 0, 0, 0);
    }

    float al[4];
#pragma unroll
    for (int r = 0; r < 4; ++r) {
      const int qg = qt * 64 + wid * 16 + quad * 4 + r;
      float sv[4];
      float mx = -3e38f;
#pragma unroll
      for (int nt = 0; nt < 4; ++nt) {
        float s = sacc[nt][r] * 0.125f;
        int kg = kt * 64 + nt * 16 + l16;
        if (kg > qg) s = -1e30f;
        sv[nt] = s;
        mx = fmaxf(mx, s);
      }
      mx = fmaxf(mx, __shfl_xor(mx, 1));
      mx = fmaxf(mx, __shfl_xor(mx, 2));
      mx = fmaxf(mx, __shfl_xor(mx, 4));
      mx = fmaxf(mx, __shfl_xor(mx, 8));
      float mn = fmaxf(mrun[r], mx);
      float a = __expf(mrun[r] - mn);
      float ps = 0.f;
#pragma unroll
      for (int nt = 0; nt < 4; ++nt) {
        float p = __expf(sv[nt] - mn);
        ps += p;
        Ps[wid * 16 + quad * 4 + r][nt * 16 + l16] = f2bf(p);
      }
      ps += __shfl_xor(ps, 1);
      ps += __shfl_xor(ps, 2);
      ps += __shfl_xor(ps, 4);
      ps += __shfl_xor(ps, 8);
      lrun[r] = lrun[r] * a + ps;
      mrun[r] = mn;
      al[r] = a;
    }
#pragma unroll
    for (int nt = 0; nt < 4; ++nt)
#pragma unroll
      for (int r = 0; r < 4; ++r) oacc[nt][r] *= al[r];

#pragma unroll
    for (int ks = 0; ks < 2; ++ks) {
      bf16x8 pa = *(const bf16x8*)(&Ps[wid * 16 + l16][ks * 32 + quad * 8]);
#pragma unroll
      for (int nt = 0; nt < 4; ++nt) {
        bf16x8 vb = *(const bf16x8*)(&Vs[(nt * 16 + l16) * 64 + (((ks * 4 + quad) ^ sx) * 8)]);
        oacc[nt] = __builtin_amdgcn_mfma_f32_16x16x32_bf16(pa, vb, oacc[nt], 0, 0, 0);
      }
    }
  }

#pragma unroll
  for (int nt = 0; nt < 4; ++nt)
#pragma unroll
    for (int r = 0; r < 4; ++r) {
      float o = oacc[nt][r] / lrun[r];
      int srow = qt * 64 + wid * 16 + quad * 4 + r;
      int col = h * 64 + nt * 16 + l16;
      Ob[(size_t)srow * 2048 + col] = f2bf(o);
    }
}

// ---------------- launcher ----------------
extern "C" void kernel_launch(void* const* d_in, const int* in_sizes, int n_in,
                              void* d_out, int out_size, void* d_ws, size_t ws_size,
                              hipStream_t stream) {
  (void)in_sizes; (void)n_in; (void)out_size;
  const float* hidden = (const float*)d_in[0];
  const float* cosb   = (const float*)d_in[1];
  const float* sinb   = (const float*)d_in[2];
  const int*   pos    = (const int*)d_in[3];
  const float* Wq     = (const float*)d_in[4];
  const float* Wk     = (const float*)d_in[5];
  const float* Wv     = (const float*)d_in[6];
  const float* Wo     = (const float*)d_in[7];
  const float* tWq    = (const float*)d_in[8];
  const float* tWv    = (const float*)d_in[9];
  const float* alpha  = (const float*)d_in[10];
  float* out = (float*)d_out;

  // split-K config tiered on workspace size (constant across calls -> graph-safe)
  const bool big = ws_size >= (size_t)120 * 1024 * 1024;
  const int Pq = big ? 2 : 1;    // QKV gemm K-splits  (grid 768 = 3/CU)
  const int Pt = big ? 16 : 1;   // tok gemm K-splits  (grid 128)
  const int Po = big ? 3 : 1;    // out gemm K-splits  (grid 768 = 3/CU)

  char* ws = (char*)d_ws;
  size_t off = 0;
  auto alloc = [&](size_t bytes) -> void* {
    void* p = ws + off;
    off += (bytes + 255) & ~(size_t)255;
    return p;
  };
  // static (live across most of the call)
  u16*   WoT   = (u16*)alloc(2048ull * 2048 * 2);
  u16*   Tt    = (u16*)alloc(64ull * 3072 * 2);
  u16*   Qb    = (u16*)alloc(32ull * 2048 * 64 * 2);
  u16*   Kb    = (u16*)alloc(8ull * 2048 * 64 * 2);
  u16*   Vt    = (u16*)alloc(8ull * 64 * 2048 * 2);
  u16*   Ob    = (u16*)alloc(2048ull * 2048 * 2);
  u16*   featb = (u16*)alloc(2048ull * 3072 * 2);
  float* tokq  = (float*)alloc(2048ull * 32 * 4);
  float* tokv  = (float*)alloc(2048ull * 32 * 4);
  u16*   Vb    = big ? (u16*)alloc(8ull * 2048 * 64 * 2) : nullptr;
  // early region (dead after prep) — late buffers alias its start
  size_t E = off;
  u16*   Xb      = (u16*)alloc(2048ull * 2048 * 2);
  u16*   WqkvT   = (u16*)alloc(3072ull * 2048 * 2);
  float* qkvPart = (float*)alloc((size_t)Pq * 2048 * 3072 * 4);
  float* qkv     = qkvPart;                 // slice 0; reduce sums in-place
  float* tokPart = (float*)(ws + E);        // aliases Xb (dead after QKV gemm)
  float* outPart = (float*)(ws + E);        // aliases early region (dead after prep)

  // 1) conversions / weight transposes
  cvt_bf16<<<2048, 256, 0, stream>>>(hidden, Xb, 2048 * 2048 / 8);
  transpose_cvt<<<dim3(32, 32), 256, 0, stream>>>(Wq, WqkvT, 2048, 2048);
  transpose_cvt<<<dim3(8, 32), 256, 0, stream>>>(Wk, WqkvT + 2048ull * 2048, 2048, 512);
  transpose_cvt<<<dim3(8, 32), 256, 0, stream>>>(Wv, WqkvT + 2560ull * 2048, 2048, 512);
  transpose_cvt<<<dim3(32, 32), 256, 0, stream>>>(Wo, WoT, 2048, 2048);
  transpose_cvt<<<dim3(1, 48), 256, 0, stream>>>(tWq, Tt, 3072, 32);
  transpose_cvt<<<dim3(1, 48), 256, 0, stream>>>(tWv, Tt + 32ull * 3072, 3072, 32);

  // 2) QKV projection, split-K partials + gelu reduce
  gemm_bt<2, 2><<<dim3(24, 16, Pq), 256, 0, stream>>>(
      Xb, WqkvT, qkvPart, 2048, 3072, 2048, (32 + Pq - 1) / Pq);
  reduce_gelu<<<6144, 256, 0, stream>>>(qkvPart, Pq, 2048 * 3072 / 4, featb);

  // 3) tok head GEMM + tanh reduce
  gemm_bt<4, 1><<<dim3(1, 8, Pt), 256, 0, stream>>>(
      featb, Tt, tokPart, 2048, 64, 3072, (48 + Pt - 1) / Pt);
  reduce_tanh<<<512, 256, 0, stream>>>(tokPart, Pt, 2048 * 64, tokq, tokv);

  // 4) tau + rope + layout prep (+ V transpose when big)
  prep_qkv<<<2048, 256, 0, stream>>>(qkv, tokq, tokv, alpha, cosb, sinb, pos,
                                     Qb, Kb, Vt, Vb);
  if (big) vtrans<<<dim3(32, 8), 256, 0, stream>>>(Vb, Vt);

  // 5) causal flash attention
  flash_attn<<<dim3(32, 32), 256, 0, stream>>>(Qb, Kb, Vt, Ob);

  // 6) output projection, split-K partials + reduce into d_out
  gemm_bt<2, 2><<<dim3(16, 16, Po), 256, 0, stream>>>(
      Ob, WoT, outPart, 2048, 2048, 2048, (32 + Po - 1) / Po);
  reduce_add<<<4096, 256, 0, stream>>>(outPart, Po, 2048 * 2048 / 4, out);
}

// Round 3
// 355.377 us; speedup vs baseline: 2.0000x; 1.0685x over previous
//
#include <hip/hip_runtime.h>
#include <cmath>

typedef __bf16 bf16x8 __attribute__((ext_vector_type(8)));
typedef float f32x4 __attribute__((ext_vector_type(4)));
typedef unsigned short u16;
typedef unsigned int u32;

__device__ __forceinline__ u16 f2bf(float f) {
  union { float f; unsigned int u; } v; v.f = f;
  unsigned int u = v.u;
  return (u16)((u + 0x7FFFu + ((u >> 16) & 1u)) >> 16);
}

__device__ __forceinline__ float geluf(float x) {
  return 0.5f * x * (1.0f + erff(x * 0.7071067811865475f));
}

// async global->LDS, 16B per lane. LDS dest = wave-uniform base + lane*16.
__device__ __forceinline__ void gl_lds16(const void* g, void* l) {
  __builtin_amdgcn_global_load_lds(
      (const __attribute__((address_space(1))) u32*)g,
      (__attribute__((address_space(3))) u32*)l, 16, 0, 0);
}

// ---------------- elementwise f32 -> bf16 (8 elems/thread) ----------------
__global__ __launch_bounds__(256) void cvt_bf16(const float* __restrict__ in,
                                                u16* __restrict__ out, int n8) {
  int i = blockIdx.x * 256 + threadIdx.x;
  if (i >= n8) return;
  const float4* p = (const float4*)in + 2 * (size_t)i;
  float4 a = p[0], b = p[1];
  uint4 o;
  o.x = (unsigned)f2bf(a.x) | ((unsigned)f2bf(a.y) << 16);
  o.y = (unsigned)f2bf(a.z) | ((unsigned)f2bf(a.w) << 16);
  o.z = (unsigned)f2bf(b.x) | ((unsigned)f2bf(b.y) << 16);
  o.w = (unsigned)f2bf(b.z) | ((unsigned)f2bf(b.w) << 16);
  ((uint4*)out)[i] = o;
}

// ---------- LDS-tiled transpose + cvt: in (R x C) f32 -> out (C x R) bf16 ----------
__global__ __launch_bounds__(256) void transpose_cvt(const float* __restrict__ in,
                                                     u16* __restrict__ out,
                                                     int R, int C) {
  __shared__ float tile[64][65];
  const int t = threadIdx.x;
  const int c0 = blockIdx.x * 64, r0 = blockIdx.y * 64;
  const int lr = t >> 6, lc = t & 63;
#pragma unroll
  for (int p = 0; p < 16; ++p) {
    int r = p * 4 + lr;
    float v = 0.f;
    if (r0 + r < R && c0 + lc < C) v = in[(size_t)(r0 + r) * C + c0 + lc];
    tile[r][lc] = v;
  }
  __syncthreads();
#pragma unroll
  for (int p = 0; p < 16; ++p) {
    int c = p * 4 + lr;
    if (c0 + c < C && r0 + lc < R)
      out[(size_t)(c0 + c) * R + r0 + lc] = f2bf(tile[lc][c]);
  }
}

// ---------------- bf16 MFMA GEMM: Cpart[z] = A(MxK) * Bt(NxK)^T over K-chunk z --------
template <int WR, int WC>
__global__ __launch_bounds__(256, 3) void gemm_bt(const u16* __restrict__ A,
                                                  const u16* __restrict__ Bt,
                                                  float* __restrict__ Cpart,
                                                  int M, int N, int K, int kPer) {
  constexpr int BM = WR * 64, BN = WC * 64;
  __shared__ __attribute__((aligned(16))) u16 As[BM * 64];
  __shared__ __attribute__((aligned(16))) u16 Bs[BN * 64];
  const int tid = threadIdx.x, wid = tid >> 6, lane = tid & 63;
  const int l16 = lane & 15, quad = lane >> 4;
  const int wm = (wid % WR) * 64, wn = (wid / WR) * 64;
  const int m0 = blockIdx.y * BM, n0 = blockIdx.x * BN;
  const int kIters = K >> 6;
  const int kStart = blockIdx.z * kPer;
  const int kEnd = (kStart + kPer < kIters) ? (kStart + kPer) : kIters;

  const int lrow = lane >> 3;
  const int swz = (lane & 7) ^ lrow;
  const u16* gAb = A + (size_t)m0 * K + (size_t)swz * 8;
  const u16* gBb = Bt + (size_t)n0 * K + (size_t)swz * 8;
  const int sx = l16 & 7;

  f32x4 acc[4][4] = {};
  for (int kt = kStart; kt < kEnd; ++kt) {
    __syncthreads();
    const u16* gA = gAb + (size_t)kt * 64;
    const u16* gB = gBb + (size_t)kt * 64;
#pragma unroll
    for (int j = 0; j < BM / 32; ++j) {
      int i = wid * (BM / 32) + j;
      gl_lds16(gA + (size_t)(i * 8 + lrow) * K, &As[i * 512]);
    }
#pragma unroll
    for (int j = 0; j < BN / 32; ++j) {
      int i = wid * (BN / 32) + j;
      gl_lds16(gB + (size_t)(i * 8 + lrow) * K, &Bs[i * 512]);
    }
    __syncthreads();
    bf16x8 af[4][2], bfr[4][2];
#pragma unroll
    for (int mt = 0; mt < 4; ++mt)
#pragma unroll
      for (int ks = 0; ks < 2; ++ks)
        af[mt][ks] = *(const bf16x8*)(&As[(wm + mt * 16 + l16) * 64 +
                                          (((ks * 4 + quad) ^ sx) * 8)]);
#pragma unroll
    for (int nt = 0; nt < 4; ++nt)
#pragma unroll
      for (int ks = 0; ks < 2; ++ks)
        bfr[nt][ks] = *(const bf16x8*)(&Bs[(wn + nt * 16 + l16) * 64 +
                                           (((ks * 4 + quad) ^ sx) * 8)]);
#pragma unroll
    for (int mt = 0; mt < 4; ++mt)
#pragma unroll
      for (int nt = 0; nt < 4; ++nt)
#pragma unroll
        for (int ks = 0; ks < 2; ++ks)
          acc[mt][nt] = __builtin_amdgcn_mfma_f32_16x16x32_bf16(
              af[mt][ks], bfr[nt][ks], acc[mt][nt], 0, 0, 0);
  }

  float* C = Cpart + (size_t)blockIdx.z * M * N;
#pragma unroll
  for (int mt = 0; mt < 4; ++mt)
#pragma unroll
    for (int nt = 0; nt < 4; ++nt)
#pragma unroll
      for (int r = 0; r < 4; ++r) {
        int row = m0 + wm + mt * 16 + quad * 4 + r;
        int col = n0 + wn + nt * 16 + l16;
        C[(size_t)row * N + col] = acc[mt][nt][r];
      }
}

// ---------------- reduce kernels (split-K epilogues) ----------------
__global__ __launch_bounds__(256) void reduce_gelu(float* __restrict__ base, int P,
                                                   int n4, u16* __restrict__ gout) {
  int i = blockIdx.x * 256 + threadIdx.x;
  if (i >= n4) return;
  size_t n = (size_t)n4 * 4;
  float4 v = ((const float4*)base)[i];
  for (int p = 1; p < P; ++p) {
    float4 w = ((const float4*)(base + (size_t)p * n))[i];
    v.x += w.x; v.y += w.y; v.z += w.z; v.w += w.w;
  }
  if (P > 1) ((float4*)base)[i] = v;
  uint2 o;
  o.x = (u32)f2bf(geluf(v.x)) | ((u32)f2bf(geluf(v.y)) << 16);
  o.y = (u32)f2bf(geluf(v.z)) | ((u32)f2bf(geluf(v.w)) << 16);
  ((uint2*)gout)[i] = o;
}

__global__ __launch_bounds__(256) void reduce_add(const float* __restrict__ base, int P,
                                                  int n4, float* __restrict__ dst) {
  int i = blockIdx.x * 256 + threadIdx.x;
  if (i >= n4) return;
  size_t n = (size_t)n4 * 4;
  float4 v = ((const float4*)base)[i];
  for (int p = 1; p < P; ++p) {
    float4 w = ((const float4*)(base + (size_t)p * n))[i];
    v.x += w.x; v.y += w.y; v.z += w.z; v.w += w.w;
  }
  ((float4*)dst)[i] = v;
}

__global__ __launch_bounds__(256) void reduce_tanh(const float* __restrict__ base, int P,
                                                   int n, float* __restrict__ tokq,
                                                   float* __restrict__ tokv) {
  int i = blockIdx.x * 256 + threadIdx.x;
  if (i >= n) return;
  float v = base[i];
  for (int p = 1; p < P; ++p) v += base[(size_t)p * n + i];
  float t = tanhf(v);
  int col = i & 63, row = i >> 6;
  if (col < 32) tokq[row * 32 + col] = t;
  else          tokv[row * 32 + (col - 32)] = t;
}

// ---------------- prep: tau scaling + RoPE + layouts for attention ----------------
// Q is pre-scaled by 0.125*log2(e) so flash softmax runs in exp2 domain.
#define QSCALE 0.18033688011112042f
__global__ __launch_bounds__(256) void prep_qkv(const float* __restrict__ qkv,
                                                const float* __restrict__ tokq,
                                                const float* __restrict__ tokv,
                                                const float* __restrict__ alpha,
                                                const float* __restrict__ cosb,
                                                const float* __restrict__ sinb,
                                                const int* __restrict__ pos_ids,
                                                u16* __restrict__ Qb,
                                                u16* __restrict__ Kb,
                                                u16* __restrict__ Vt,
                                                u16* __restrict__ Vb) {
  const int s = blockIdx.x;
  const int tid = threadIdx.x;
  __shared__ float cs[16], sn[16], tq_s[32], tv_s[32];
  if (tid < 16) { cs[tid] = cosb[s * 16 + tid]; sn[tid] = sinb[s * 16 + tid]; }
  if (tid < 32) {
    float p = (float)pos_ids[s] + 1.0f;
    float sig = 1.0f / (1.0f + __expf(-alpha[tid] * logf(p)));
    float taupos = 0.5f + sig;
    tq_s[tid] = (tokq[s * 32 + tid] + taupos) * QSCALE;
    tv_s[tid] = tokv[s * 32 + tid] + taupos;
  }
  __syncthreads();
  const float* row = qkv + (size_t)s * 3072;

  for (int idx = tid; idx < 2048; idx += 256) {
    int h = idx >> 6, d = idx & 63;
    float tq = tq_s[h];
    float v;
    if (d < 32) {
      int i = d >> 1;
      float xr = row[h * 64 + i] * tq, xi = row[h * 64 + 16 + i] * tq;
      v = (d & 1) ? (xr * sn[i] + xi * cs[i]) : (xr * cs[i] - xi * sn[i]);
    } else v = row[h * 64 + d] * tq;
    Qb[((size_t)h * 2048 + s) * 64 + d] = f2bf(v);
  }
  for (int idx = tid; idx < 512; idx += 256) {
    int h = idx >> 6, d = idx & 63;
    const float* kr = row + 2048;
    float v;
    if (d < 32) {
      int i = d >> 1;
      float xr = kr[h * 64 + i], xi = kr[h * 64 + 16 + i];
      v = (d & 1) ? (xr * sn[i] + xi * cs[i]) : (xr * cs[i] - xi * sn[i]);
    } else v = kr[h * 64 + d];
    Kb[((size_t)h * 2048 + s) * 64 + d] = f2bf(v);
  }
  for (int idx = tid; idx < 512; idx += 256) {
    int h = idx >> 6, d = idx & 63;
    float v = row[2560 + h * 64 + d] * tv_s[h];
    u16 b = f2bf(v);
    if (Vb) Vb[((size_t)h * 2048 + s) * 64 + d] = b;
    else    Vt[((size_t)h * 64 + d) * 2048 + s] = b;
  }
}

// ---------------- bf16 transpose Vb[h][s][d] -> Vt[h][d][s] ----------------
__global__ __launch_bounds__(256) void vtrans(const u16* __restrict__ Vb,
                                              u16* __restrict__ Vt) {
  __shared__ u16 t[64][68];
  const int s0 = blockIdx.x * 64, h = blockIdx.y;
  const int tid = threadIdx.x;
  const u16* src = Vb + ((size_t)h * 2048 + s0) * 64;
#pragma unroll
  for (int p = 0; p < 4; ++p) {
    int v = p * 256 + tid;
    int r = v >> 4, c = (v & 15) * 4;
    uint2 w = *(const uint2*)(src + (size_t)r * 64 + c);
    t[r][c] = (u16)(w.x & 0xffff); t[r][c + 1] = (u16)(w.x >> 16);
    t[r][c + 2] = (u16)(w.y & 0xffff); t[r][c + 3] = (u16)(w.y >> 16);
  }
  __syncthreads();
  u16* dst = Vt + (size_t)h * 64 * 2048 + s0;
#pragma unroll
  for (int p = 0; p < 4; ++p) {
    int v = p * 256 + tid;
    int d = v >> 4, s = (v & 15) * 4;
    uint2 w;
    w.x = (u32)t[s][d] | ((u32)t[s + 1][d] << 16);
    w.y = (u32)t[s + 2][d] | ((u32)t[s + 3][d] << 16);
    *(uint2*)(dst + (size_t)d * 2048 + s) = w;
  }
}

// ---------------- flash attention v2 ----------------
// Q-tile 128/block (4 waves x 32 rows), K-tile 64, double-buffered K/V staging,
// single barrier/iter, exp2-domain softmax, l via ones-column MFMA.
__global__ __launch_bounds__(256, 2) void flash_attn(const u16* __restrict__ Qb,
                                                     const u16* __restrict__ Kb,
                                                     const u16* __restrict__ Vt,
                                                     u16* __restrict__ Ob) {
  __shared__ __attribute__((aligned(16))) u16 KsB[2][4096];
  __shared__ __attribute__((aligned(16))) u16 VsB[2][4096];
  __shared__ __attribute__((aligned(16))) u16 Ps[128 * 72];
  __shared__ __attribute__((aligned(16))) u16 Vone[1024];
  const int idx = blockIdx.x;
  const int b = 15 - (idx >> 5);          // reversed: heaviest first
  const int h = idx & 31, kvh = h >> 2;
  const int tid = threadIdx.x, wid = tid >> 6, lane = tid & 63;
  const int l16 = lane & 15, quad = lane >> 4;
  const int lrow = lane >> 3, swz = (lane & 7) ^ lrow, sx = l16 & 7;

  // ones-column V-extension tile: B[n][k] swizzled like Vs; n==0 col = 1.0
  for (int i = tid; i < 1024; i += 256) {
    int n = i >> 6, k = i & 63;
    Vone[n * 64 + ((((k >> 3) ^ (n & 7)) << 3) | (k & 7))] = (n == 0) ? 0x3F80 : 0;
  }

  const int q0 = b * 128 + wid * 32;
  bf16x8 qf[2][2];
#pragma unroll
  for (int mt = 0; mt < 2; ++mt)
#pragma unroll
    for (int ks = 0; ks < 2; ++ks)
      qf[mt][ks] = *(const bf16x8*)(Qb + ((size_t)h * 2048 + q0 + mt * 16 + l16) * 64 +
                                    ks * 32 + quad * 8);

  f32x4 oacc[2][4] = {};
  f32x4 oaccE[2] = {};
  float mrun[2][4];
#pragma unroll
  for (int mt = 0; mt < 2; ++mt)
#pragma unroll
    for (int r = 0; r < 4; ++r) mrun[mt][r] = -3e38f;

  const int kvT = 2 * b + 2;
  const u16* kgb = Kb + ((size_t)kvh * 2048) * 64;
  const u16* vgb = Vt + (size_t)kvh * 64 * 2048;

#define FA_STAGE(KT, BUF)                                                         \
  {                                                                               \
    const u16* kg_ = kgb + (size_t)(KT)*64 * 64;                                  \
    const u16* vg_ = vgb + (size_t)(KT)*64;                                       \
    _Pragma("unroll") for (int j = 0; j < 2; ++j) {                               \
      int i_ = wid * 2 + j;                                                       \
      gl_lds16(kg_ + (size_t)(i_ * 8 + lrow) * 64 + swz * 8, &KsB[BUF][i_ * 512]);\
      gl_lds16(vg_ + (size_t)(i_ * 8 + lrow) * 2048 + swz * 8, &VsB[BUF][i_ * 512]);\
    }                                                                             \
  }

  FA_STAGE(0, 0)
  for (int kt = 0; kt < kvT; ++kt) {
    const int cur = kt & 1;
    __syncthreads();  // drains this tile's staging; protects buffer swap
    if (kt + 1 < kvT) FA_STAGE(kt + 1, cur ^ 1)
    const u16* Ks = KsB[cur];
    const u16* Vs = VsB[cur];

    // S = Q K^T  (pre-scaled to exp2 domain)
    f32x4 sacc[2][4] = {};
#pragma unroll
    for (int nt = 0; nt < 4; ++nt) {
      bf16x8 b0 = *(const bf16x8*)(Ks + (nt * 16 + l16) * 64 + ((quad ^ sx) << 3));
      bf16x8 b1 = *(const bf16x8*)(Ks + (nt * 16 + l16) * 64 + (((4 + quad) ^ sx) << 3));
      sacc[0][nt] = __builtin_amdgcn_mfma_f32_16x16x32_bf16(qf[0][0], b0, sacc[0][nt], 0, 0, 0);
      sacc[0][nt] = __builtin_amdgcn_mfma_f32_16x16x32_bf16(qf[0][1], b1, sacc[0][nt], 0, 0, 0);
      sacc[1][nt] = __builtin_amdgcn_mfma_f32_16x16x32_bf16(qf[1][0], b0, sacc[1][nt], 0, 0, 0);
      sacc[1][nt] = __builtin_amdgcn_mfma_f32_16x16x32_bf16(qf[1][1], b1, sacc[1][nt], 0, 0, 0);
    }

    const bool msk = (kt >= 2 * b);  // only last two tiles need causal masking
    f32x4 alv[2];
#pragma unroll
    for (int mt = 0; mt < 2; ++mt) {
#pragma unroll
      for (int r = 0; r < 4; ++r) {
        float sv[4];
        if (msk) {
          const int qg = q0 + mt * 16 + quad * 4 + r;
#pragma unroll
          for (int nt = 0; nt < 4; ++nt) {
            float s = sacc[mt][nt][r];
            if (kt * 64 + nt * 16 + l16 > qg) s = -1e9f;
            sv[nt] = s;
          }
        } else {
#pragma unroll
          for (int nt = 0; nt < 4; ++nt) sv[nt] = sacc[mt][nt][r];
        }
        float mx = fmaxf(fmaxf(sv[0], sv[1]), fmaxf(sv[2], sv[3]));
        mx = fmaxf(mx, __shfl_xor(mx, 1));
        mx = fmaxf(mx, __shfl_xor(mx, 2));
        mx = fmaxf(mx, __shfl_xor(mx, 4));
        mx = fmaxf(mx, __shfl_xor(mx, 8));
        float mn = fmaxf(mrun[mt][r], mx);
        alv[mt][r] = __builtin_amdgcn_exp2f(mrun[mt][r] - mn);
        mrun[mt][r] = mn;
        const int prow = wid * 32 + mt * 16 + quad * 4 + r;
#pragma unroll
        for (int nt = 0; nt < 4; ++nt) {
          float p = __builtin_amdgcn_exp2f(sv[nt] - mn);
          *(__bf16*)&Ps[prow * 72 + nt * 16 + l16] = (__bf16)p;
        }
      }
    }
#pragma unroll
    for (int mt = 0; mt < 2; ++mt) {
#pragma unroll
      for (int nt = 0; nt < 4; ++nt) oacc[mt][nt] *= alv[mt];
      oaccE[mt] *= alv[mt];
    }

    // O += P V ; l-sums via ones tile (same-wave LDS write->read, no barrier)
#pragma unroll
    for (int ks = 0; ks < 2; ++ks) {
      bf16x8 pa0 = *(const bf16x8*)(Ps + (wid * 32 + l16) * 72 + ks * 32 + quad * 8);
      bf16x8 pa1 = *(const bf16x8*)(Ps + (wid * 32 + 16 + l16) * 72 + ks * 32 + quad * 8);
      bf16x8 vo = *(const bf16x8*)(Vone + l16 * 64 + (((ks * 4 + quad) ^ sx) << 3));
#pragma unroll
      for (int nt = 0; nt < 4; ++nt) {
        bf16x8 vb = *(const bf16x8*)(Vs + (nt * 16 + l16) * 64 + (((ks * 4 + quad) ^ sx) << 3));
        oacc[0][nt] = __builtin_amdgcn_mfma_f32_16x16x32_bf16(pa0, vb, oacc[0][nt], 0, 0, 0);
        oacc[1][nt] = __builtin_amdgcn_mfma_f32_16x16x32_bf16(pa1, vb, oacc[1][nt], 0, 0, 0);
      }
      oaccE[0] = __builtin_amdgcn_mfma_f32_16x16x32_bf16(pa0, vo, oaccE[0], 0, 0, 0);
      oaccE[1] = __builtin_amdgcn_mfma_f32_16x16x32_bf16(pa1, vo, oaccE[1], 0, 0, 0);
    }
  }
#undef FA_STAGE

  // epilogue: broadcast l from col-0 lanes, normalize, store
#pragma unroll
  for (int mt = 0; mt < 2; ++mt) {
    float lb[4];
#pragma unroll
    for (int r = 0; r < 4; ++r) lb[r] = __shfl(oaccE[mt][r], lane & 48);
#pragma unroll
    for (int nt = 0; nt < 4; ++nt)
#pragma unroll
      for (int r = 0; r < 4; ++r) {
        float o = oacc[mt][nt][r] / lb[r];
        int srow = q0 + mt * 16 + quad * 4 + r;
        Ob[(size_t)srow * 2048 + h * 64 + nt * 16 + l16] = f2bf(o);
      }
  }
}

// ---------------- launcher ----------------
extern "C" void kernel_launch(void* const* d_in, const int* in_sizes, int n_in,
                              void* d_out, int out_size, void* d_ws, size_t ws_size,
                              hipStream_t stream) {
  (void)in_sizes; (void)n_in; (void)out_size;
  const float* hidden = (const float*)d_in[0];
  const float* cosb   = (const float*)d_in[1];
  const float* sinb   = (const float*)d_in[2];
  const int*   pos    = (const int*)d_in[3];
  const float* Wq     = (const float*)d_in[4];
  const float* Wk     = (const float*)d_in[5];
  const float* Wv     = (const float*)d_in[6];
  const float* Wo     = (const float*)d_in[7];
  const float* tWq    = (const float*)d_in[8];
  const float* tWv    = (const float*)d_in[9];
  const float* alpha  = (const float*)d_in[10];
  float* out = (float*)d_out;

  const bool big = ws_size >= (size_t)120 * 1024 * 1024;
  const int Pq = big ? 2 : 1;
  const int Pt = big ? 16 : 1;
  const int Po = big ? 3 : 1;

  char* ws = (char*)d_ws;
  size_t off = 0;
  auto alloc = [&](size_t bytes) -> void* {
    void* p = ws + off;
    off += (bytes + 255) & ~(size_t)255;
    return p;
  };
  u16*   WoT   = (u16*)alloc(2048ull * 2048 * 2);
  u16*   Tt    = (u16*)alloc(64ull * 3072 * 2);
  u16*   Qb    = (u16*)alloc(32ull * 2048 * 64 * 2);
  u16*   Kb    = (u16*)alloc(8ull * 2048 * 64 * 2);
  u16*   Vt    = (u16*)alloc(8ull * 64 * 2048 * 2);
  u16*   Ob    = (u16*)alloc(2048ull * 2048 * 2);
  u16*   featb = (u16*)alloc(2048ull * 3072 * 2);
  float* tokq  = (float*)alloc(2048ull * 32 * 4);
  float* tokv  = (float*)alloc(2048ull * 32 * 4);
  u16*   Vb    = big ? (u16*)alloc(8ull * 2048 * 64 * 2) : nullptr;
  size_t E = off;
  u16*   Xb      = (u16*)alloc(2048ull * 2048 * 2);
  u16*   WqkvT   = (u16*)alloc(3072ull * 2048 * 2);
  float* qkvPart = (float*)alloc((size_t)Pq * 2048 * 3072 * 4);
  float* qkv     = qkvPart;
  float* tokPart = (float*)(ws + E);
  float* outPart = (float*)(ws + E);

  cvt_bf16<<<2048, 256, 0, stream>>>(hidden, Xb, 2048 * 2048 / 8);
  transpose_cvt<<<dim3(32, 32), 256, 0, stream>>>(Wq, WqkvT, 2048, 2048);
  transpose_cvt<<<dim3(8, 32), 256, 0, stream>>>(Wk, WqkvT + 2048ull * 2048, 2048, 512);
  transpose_cvt<<<dim3(8, 32), 256, 0, stream>>>(Wv, WqkvT + 2560ull * 2048, 2048, 512);
  transpose_cvt<<<dim3(32, 32), 256, 0, stream>>>(Wo, WoT, 2048, 2048);
  transpose_cvt<<<dim3(1, 48), 256, 0, stream>>>(tWq, Tt, 3072, 32);
  transpose_cvt<<<dim3(1, 48), 256, 0, stream>>>(tWv, Tt + 32ull * 3072, 3072, 32);

  gemm_bt<2, 2><<<dim3(24, 16, Pq), 256, 0, stream>>>(
      Xb, WqkvT, qkvPart, 2048, 3072, 2048, (32 + Pq - 1) / Pq);
  reduce_gelu<<<6144, 256, 0, stream>>>(qkvPart, Pq, 2048 * 3072 / 4, featb);

  gemm_bt<4, 1><<<dim3(1, 8, Pt), 256, 0, stream>>>(
      featb, Tt, tokPart, 2048, 64, 3072, (48 + Pt - 1) / Pt);
  reduce_tanh<<<512, 256, 0, stream>>>(tokPart, Pt, 2048 * 64, tokq, tokv);

  prep_qkv<<<2048, 256, 0, stream>>>(qkv, tokq, tokv, alpha, cosb, sinb, pos,
                                     Qb, Kb, Vt, Vb);
  if (big) vtrans<<<dim3(32, 8), 256, 0, stream>>>(Vb, Vt);

  flash_attn<<<512, 256, 0, stream>>>(Qb, Kb, Vt, Ob);

  gemm_bt<2, 2><<<dim3(16, 16, Po), 256, 0, stream>>>(
      Ob, WoT, outPart, 2048, 2048, 2048, (32 + Po - 1) / Po);
  reduce_add<<<4096, 256, 0, stream>>>(outPart, Po, 2048 * 2048 / 4, out);
}